// Round 8
// baseline (118.667 us; speedup 1.0000x reference)
//
#include <hip/hip_runtime.h>
#include <math.h>

// Problem constants (B, NA, NO, D, C, T) = (2048, 64, 64, 128, 64, 3)
#define NB 2048
#define NNODES 129
#define ND 128
#define NC 64
#define BPB 4              // batches per block (software pipeline)
#define NBLK (NB / BPB)    // 512 blocks -> 2 blocks/CU, whole grid resident

typedef unsigned int u32;

// ws float layout:
//  [0]              : mask-dtype flag (int)
//  [16 .. 16+1152)  : u[j*3+i][d]  (9 x 128)   u = W[j] @ a1[i]
//  [1168 .. +384)   : v2[i][d]     (3 x 128)   v2 = W[i] @ a2[i]

__device__ __forceinline__ bool mask_at(const void* m, int flag, int idx) {
  if (flag == 1) return ((const unsigned char*)m)[idx] != 0;
  if (flag == 2) return ((const float*)m)[idx] != 0.0f;
  return ((const int*)m)[idx] != 0;
}

__device__ __forceinline__ void fma4(float4& a, float s, float4 v) {
  a.x = fmaf(s, v.x, a.x); a.y = fmaf(s, v.y, a.y);
  a.z = fmaf(s, v.z, a.z); a.w = fmaf(s, v.w, a.w);
}
__device__ __forceinline__ float dot4(float4 a, float4 b) {
  return a.x * b.x + a.y * b.y + a.z * b.z + a.w * b.w;
}
__device__ __forceinline__ void qred4(float4& a) {   // reduce over lane^1, lane^2
  a.x += __shfl_xor(a.x, 1); a.y += __shfl_xor(a.y, 1);
  a.z += __shfl_xor(a.z, 1); a.w += __shfl_xor(a.w, 1);
  a.x += __shfl_xor(a.x, 2); a.y += __shfl_xor(a.y, 2);
  a.z += __shfl_xor(a.z, 2); a.w += __shfl_xor(a.w, 2);
}

__global__ void hetgat_precomp(const float* __restrict__ W, const float* __restrict__ a,
                               const void* __restrict__ mask, float* __restrict__ ws) {
  int gidx = blockIdx.x * 256 + threadIdx.x;
  if (blockIdx.x == 6) {
    if (threadIdx.x == 0) {
      const unsigned char* mb = (const unsigned char*)mask;
      const unsigned int* mw = (const unsigned int*)mask;
      bool bytes01 = true, words01 = true, wordsF = true;
      for (int i = 0; i < 256; ++i) { if (mb[i] > 1) bytes01 = false; }
      for (int i = 0; i < 64; ++i) {
        unsigned int w = mw[i];
        if (w != 0u && w != 1u) words01 = false;
        if (w != 0u && w != 0x3F800000u) wordsF = false;
      }
      int flag;
      if (words01) flag = 0;
      else if (bytes01) flag = 1;
      else if (wordsF) flag = 2;
      else flag = 1;
      ((int*)ws)[0] = flag;
    }
    return;
  }
  if (gidx < 1152) {                // u[j*3+i][d]
    int ji = gidx >> 7, d = gidx & 127;
    int j = ji / 3, i = ji - 3 * j;
    const float4* Wp = (const float4*)(W + j * 8192 + d * 64);
    const float4* ap = (const float4*)(a + i * 128);
    float s = 0.f;
#pragma unroll
    for (int c = 0; c < 16; ++c) {
      float4 w4 = Wp[c], a4 = ap[c];
      s += w4.x * a4.x + w4.y * a4.y + w4.z * a4.z + w4.w * a4.w;
    }
    ws[16 + gidx] = s;
  } else if (gidx < 1536) {         // v2[i][d]
    int rel = gidx - 1152;
    int i = rel >> 7, d = rel & 127;
    const float4* Wp = (const float4*)(W + i * 8192 + d * 64);
    const float4* ap = (const float4*)(a + i * 128 + 64);
    float s = 0.f;
#pragma unroll
    for (int c = 0; c < 16; ++c) {
      float4 w4 = Wp[c], a4 = ap[c];
      s += w4.x * a4.x + w4.y * a4.y + w4.z * a4.z + w4.w * a4.w;
    }
    ws[1168 + rel] = s;
  }
}

// LDS float offsets. hl: 129 rows x 128 f32; float4-chunk swizzle: chunk ^= row&7.
#define OFF_HL    0        // 16512
#define OFF_W2    16512    // 384 = w2[3][128]
#define OFF_ERA   16896    // 192
#define OFF_ERO   17088    // 192
#define OFF_ESW   17280    // 32
#define OFF_MSF   17312    // 4
#define OFF_GL    17316    // 384
#define OFF_V2L   17700    // 384 (persistent)
#define OFF_GPART 18084    // 1536 = gpart[4][3][128]; red[256] aliases
#define LDS_FLOATS 19620   // 78,480 B -> 2 blocks/CU
#define LDS_BYTES (LDS_FLOATS * 4)

__device__ __forceinline__ void load_masks(const void* mask, int flag, int b,
                                           int wv, int ln,
                                           bool& m0, bool& m1, bool& m2, float& ms) {
  if (wv == 0) {
    int base = b * NNODES + 1 + ln;
    m0 = mask_at(mask, flag, base);
    m1 = mask_at(mask, flag, NB * NNODES + base);
    m2 = mask_at(mask, flag, 2 * NB * NNODES + base);
  } else if (wv == 1) {
    int base = b * NNODES + 65 + ln;
    m0 = mask_at(mask, flag, base);
    m1 = mask_at(mask, flag, NB * NNODES + base);
    m2 = mask_at(mask, flag, 2 * NB * NNODES + base);
  } else if (wv == 2 && ln < 3) {
    ms = mask_at(mask, flag, (ln * NB + b) * NNODES) ? 1.f : 0.f;
  }
}

// logits from register-resident f32 row + pack row into swizzled f32 LDS
__device__ __forceinline__ void logits_pack(float* hl, float* era, float* ero,
                                            const float* v2l,
                                            const float4 (&hreg)[16],
                                            const float4 (&r0)[2], int tid) {
  const int half = tid & 1;
  const int row = (tid >> 1) + 1;        // 1..128
  float a0 = 0.f, a1 = 0.f, a2 = 0.f;
  const float4* vv = (const float4*)v2l + half * 16;
#pragma unroll
  for (int q = 0; q < 16; ++q) {
    float4 x = hreg[q];
    a0 += dot4(x, vv[q]);
    a1 += dot4(x, vv[32 + q]);
    a2 += dot4(x, vv[64 + q]);
  }
  const int s = row & 7;
#pragma unroll
  for (int q = 0; q < 16; ++q) {
    int chunk = half * 16 + q;
    *(float4*)(hl + row * 128 + ((chunk ^ s) << 2)) = hreg[q];
  }
  a0 += __shfl_xor(a0, 1);
  a1 += __shfl_xor(a1, 1);
  a2 += __shfl_xor(a2, 1);
  if (half == 0) {
    if (row <= 64) {
      era[row - 1] = a0; era[64 + row - 1] = a1; era[128 + row - 1] = a2;
    } else {
      ero[row - 65] = a0; ero[64 + row - 65] = a1; ero[128 + row - 65] = a2;
    }
  }
  if ((tid >> 6) == 3 && (tid & 63) < 16) {   // row 0 (swizzle identity)
    int l = tid & 63;
    *(float4*)(hl + ((2 * l) << 2))     = r0[0];
    *(float4*)(hl + ((2 * l + 1) << 2)) = r0[1];
  }
}

__global__ __launch_bounds__(256, 2) void hetgat_main(
    const float* __restrict__ h, const float* __restrict__ W,
    const void* __restrict__ mask, const float* __restrict__ ws,
    float* __restrict__ out) {
  extern __shared__ float lds[];
  float* hl    = lds + OFF_HL;
  float* w2    = lds + OFF_W2;
  float* era   = lds + OFF_ERA;
  float* ero   = lds + OFF_ERO;
  float* esw   = lds + OFF_ESW;
  float* msf   = lds + OFF_MSF;
  float* gl    = lds + OFF_GL;
  float* v2l   = lds + OFF_V2L;
  float* gpart = lds + OFF_GPART;
  float* red   = lds + OFF_GPART;   // alias: gpart dead when red is live

  const int tid = threadIdx.x;
  const int wv = tid >> 6, ln = tid & 63;
  const int half = tid & 1;
  const int row = (tid >> 1) + 1;
  const int flag = ((const int*)ws)[0];
  const int b0 = blockIdx.x * BPB;

  // ---- prologue: stage v2 -> LDS; load h(b0) -> regs; masks(b0) ----
  if (tid < 96) ((float4*)v2l)[tid] = ((const float4*)(ws + 1168))[tid];

  float4 hreg[16], r0reg[2];
  {
    const float* hb = h + (size_t)b0 * NNODES * ND;
    const float4* hp = (const float4*)(hb + row * ND + half * 64);
#pragma unroll
    for (int q = 0; q < 16; ++q) hreg[q] = hp[q];
    if (wv == 3 && ln < 16) {
      r0reg[0] = ((const float4*)hb)[2 * ln];
      r0reg[1] = ((const float4*)hb)[2 * ln + 1];
    }
  }
  bool mc0 = false, mc1 = false, mc2 = false; float msc = 0.f;
  load_masks(mask, flag, b0, wv, ln, mc0, mc1, mc2, msc);
  __syncthreads();                         // v2l ready
  logits_pack(hl, era, ero, v2l, hreg, r0reg, tid);
  if (wv == 2 && ln < 3) msf[ln] = msc;
  __syncthreads();                         // hl / era / ero / msf (b0) ready

  for (int j = 0; j < BPB; ++j) {
    const int b = b0 + j;
    bool mn0 = false, mn1 = false, mn2 = false; float msn = 0.f;

    // [1] issue next-b loads (hidden under phases B-D)
    if (j < BPB - 1) {
      const float* hb = h + (size_t)(b + 1) * NNODES * ND;
      const float4* hp = (const float4*)(hb + row * ND + half * 64);
#pragma unroll
      for (int q = 0; q < 16; ++q) hreg[q] = hp[q];
      if (wv == 3 && ln < 16) {
        r0reg[0] = ((const float4*)hb)[2 * ln];
        r0reg[1] = ((const float4*)hb)[2 * ln + 1];
      }
      load_masks(mask, flag, b + 1, wv, ln, mn0, mn1, mn2, msn);
    }

    // [2] phase B: e_self + collapsed softmax -> w2
    if (wv < 2) {
      if (ln < 9) {
        const float4* uu = (const float4*)(ws + 16) + ln * 32;
        const float4* h0 = (const float4*)hl;      // row 0 (f32, identity swizzle)
        float s = 0.f;
#pragma unroll 8
        for (int ch = 0; ch < 32; ++ch) s += dot4(h0[ch], uu[ch]);
        esw[wv * 16 + ln] = s;
      }
      const float* e = (wv == 0) ? era : ero;
      const float* es = esw + wv * 16;
      float ms3[3], S[3];
#pragma unroll
      for (int i = 0; i < 3; ++i) {
        float e0 = es[i], e1 = es[3 + i], e2 = es[6 + i];
        float m = fmaxf(fmaxf(e0, e1), e2);
        ms3[i] = m;
        S[i] = __expf(e0 - m) + __expf(e1 - m) + __expf(e2 - m);
      }
      float v0  = mc0 ? -INFINITY : e[ln];
      float v1  = mc1 ? -INFINITY : e[64 + ln];
      float v2v = mc2 ? -INFINITY : e[128 + ln];
      float c0 = v0 + ms3[0], c1 = v1 + ms3[1], c2 = v2v + ms3[2];
      float mx = fmaxf(fmaxf(c0, c1), c2);
      for (int off = 32; off; off >>= 1) mx = fmaxf(mx, __shfl_xor(mx, off));
      float t0 = 0.f, t1 = 0.f, t2 = 0.f;
      if (mx != -INFINITY) {
        t0 = mc0 ? 0.f : S[0] * __expf(c0 - mx);
        t1 = mc1 ? 0.f : S[1] * __expf(c1 - mx);
        t2 = mc2 ? 0.f : S[2] * __expf(c2 - mx);
      }
      float z = t0 + t1 + t2;
      for (int off = 32; off; off >>= 1) z += __shfl_xor(z, off);
      float inv = (z > 0.f) ? 1.f / z : 0.f;
      w2[wv * 64 + ln]       = t0 * inv;
      w2[128 + wv * 64 + ln] = t1 * inv;
      w2[256 + wv * 64 + ln] = t2 * inv;
    }
    __syncthreads();

    // [3] phase C: 4-wave partial weighted sums (b128 swizzled reads)
    {
      const int c = ln >> 2, rs = ln & 3;
      float4 z4 = {0.f, 0.f, 0.f, 0.f};
      float4 aL0 = z4, aL1 = z4, aL2 = z4, aH0 = z4, aH1 = z4, aH2 = z4;
#pragma unroll
      for (int g = 0; g < 8; ++g) {
        int r = 1 + wv * 32 + 4 * g + rs;    // rows 1..128 across 4 waves
        int n = r - 1;
        int sc = (c ^ (r & 7)) << 2;
        float4 xl = *(const float4*)(hl + r * 128 + sc);        // d = 4c..4c+3
        float4 xh = *(const float4*)(hl + r * 128 + 64 + sc);   // d = 64+4c..
        float w0 = w2[n], w1 = w2[128 + n], wz = w2[256 + n];
        fma4(aL0, w0, xl); fma4(aH0, w0, xh);
        fma4(aL1, w1, xl); fma4(aH1, w1, xh);
        fma4(aL2, wz, xl); fma4(aH2, wz, xh);
      }
      qred4(aL0); qred4(aL1); qred4(aL2); qred4(aH0); qred4(aH1); qred4(aH2);
      if (rs == 0) {
        float* gp = gpart + wv * 384;
        *(float4*)(gp + 0 * 128 + 4 * c) = aL0; *(float4*)(gp + 0 * 128 + 64 + 4 * c) = aH0;
        *(float4*)(gp + 1 * 128 + 4 * c) = aL1; *(float4*)(gp + 1 * 128 + 64 + 4 * c) = aH1;
        *(float4*)(gp + 2 * 128 + 4 * c) = aL2; *(float4*)(gp + 2 * 128 + 64 + 4 * c) = aH2;
      }
    }
    __syncthreads();

    // [4] reduce partials + masked self term -> gl
    if (wv < 3) {
      const int t = wv;
      float2 s0 = *(const float2*)(gpart + 0 * 384 + t * 128 + 2 * ln);
      float2 s1 = *(const float2*)(gpart + 1 * 384 + t * 128 + 2 * ln);
      float2 s2 = *(const float2*)(gpart + 2 * 384 + t * 128 + 2 * ln);
      float2 s3 = *(const float2*)(gpart + 3 * 384 + t * 128 + 2 * ln);
      float2 hs = *(const float2*)(hl + 2 * ln);   // row 0, f32
      float m = msf[t];
      float2 r;
      r.x = s0.x + s1.x + s2.x + s3.x + m * hs.x;
      r.y = s0.y + s1.y + s2.y + s3.y + m * hs.y;
      *(float2*)(gl + t * 128 + 2 * ln) = r;
    }
    __syncthreads();

    // [5] epilogue partials + next-b logits/pack (overlapped)
    {
      int q = tid >> 6, cc = tid & 63;
      float acc = 0.f;
#pragma unroll
      for (int t = 0; t < 3; ++t) {
        const float* Wp = W + t * 8192 + cc;
        const float4* g4 = (const float4*)(gl + t * 128) + q * 8;
#pragma unroll
        for (int k = 0; k < 8; ++k) {
          float4 gv = g4[k];
          int dd = q * 32 + k * 4;
          acc += gv.x * Wp[dd * 64] + gv.y * Wp[(dd + 1) * 64]
               + gv.z * Wp[(dd + 2) * 64] + gv.w * Wp[(dd + 3) * 64];
        }
      }
      red[q * 64 + cc] = acc;
    }
    if (j < BPB - 1) {
      logits_pack(hl, era, ero, v2l, hreg, r0reg, tid);   // waits hreg loads here
      if (wv == 2 && ln < 3) msf[ln] = msn;
      mc0 = mn0; mc1 = mn1; mc2 = mn2; msc = msn;
    }
    __syncthreads();

    // [6] out(b)
    if (tid < 64) {
      float x = red[tid] + red[64 + tid] + red[128 + tid] + red[192 + tid];
      out[(size_t)b * NC + tid] = (x > 0.f) ? x : expm1f(x);
    }
  }
}

extern "C" void kernel_launch(void* const* d_in, const int* in_sizes, int n_in,
                              void* d_out, int out_size, void* d_ws, size_t ws_size,
                              hipStream_t stream) {
  (void)in_sizes; (void)n_in; (void)out_size; (void)ws_size;
  const float* h   = (const float*)d_in[0];
  const float* W   = (const float*)d_in[1];
  const float* a   = (const float*)d_in[2];
  const void* mask = d_in[3];
  float* ws  = (float*)d_ws;
  float* out = (float*)d_out;

  (void)hipFuncSetAttribute((const void*)hetgat_main,
                            hipFuncAttributeMaxDynamicSharedMemorySize, LDS_BYTES);

  hetgat_precomp<<<dim3(7), dim3(256), 0, stream>>>(W, a, mask, ws);
  hetgat_main<<<dim3(NBLK), dim3(256), LDS_BYTES, stream>>>(h, W, mask, ws, out);
}